// Round 3
// baseline (708.199 us; speedup 1.0000x reference)
//
#include <hip/hip_runtime.h>
#include <hip/hip_fp16.h>

// Problem constants (fixed by the reference):
//   B=32768, N=4, F_IN=512, D=64  -> GEMM [131072 x 512] x [512 x 192]
#define BTOT   32768
#define FIN    512
#define KSTEPS 16        // 512 / 32
#define NTILES 12        // 192 / 16 (tiles 0-3 = K, 4-7 = Q, 8-11 = V)
#define WH_ELEMS (KSTEPS * NTILES * 64 * 8)   // 98304 halves
#define CHUNK_HALVES (NTILES * 64 * 8)        // old-layout chunk (per k-step)
#define KQ_HALVES (KSTEPS * 8 * 512)          // 65536 halves = 128 KiB (K,Q section)
#define KQ_BYTES  (KQ_HALVES * 2)             // 131072 B staged to LDS
#define WAVES  8
#define ROWTILES 4
#define ROWS_PER_BLOCK (WAVES * 16 * ROWTILES)  // 512
#define NBLOCKS (BTOT * 4 / ROWS_PER_BLOCK)     // 256 = 1 per CU

using half8   = __attribute__((ext_vector_type(8))) _Float16;
using floatx4 = __attribute__((ext_vector_type(4))) float;

// Async global->LDS, 16 B per lane. LDS dest is wave-uniform base + lane*16.
#define GLOAD_LDS16(gp, lp)                                                  \
    __builtin_amdgcn_global_load_lds(                                        \
        (const __attribute__((address_space(1))) void*)(gp),                 \
        (__attribute__((address_space(3))) void*)(lp), 16, 0, 0)

// Convert Wk|Wq|Wv (fp32 [512,64] each) into fp16 MFMA B-fragment order.
// New layout: K,Q section  [k][t=0..7][lane][j]  (128 KiB, staged to LDS once),
//             V  section   [k][t=0..3][lane][j]  ( 64 KiB, stays in global/L2).
// B-operand layout for mfma_f32_16x16x32_f16: lane holds B[k=(lane>>4)*8+j][n=lane&15].
__global__ void convert_w_kernel(const float* __restrict__ Wk,
                                 const float* __restrict__ Wq,
                                 const float* __restrict__ Wv,
                                 _Float16* __restrict__ Wh) {
    int idx = blockIdx.x * blockDim.x + threadIdx.x;
    if (idx >= WH_ELEMS) return;
    int j    = idx & 7;
    int lane = (idx >> 3) & 63;
    int t    = (idx >> 9) % NTILES;
    int kk   = idx / CHUNK_HALVES;
    int k = kk * 32 + (lane >> 4) * 8 + j;
    int n = t * 16 + (lane & 15);
    const float* src = (n < 64) ? Wk : (n < 128) ? Wq : Wv;
    _Float16 val = (_Float16)src[k * 64 + (n & 63)];
    size_t dst = (t < 8)
        ? ((size_t)(kk * 8 + t) * 512 + lane * 8 + j)
        : (size_t)KQ_HALVES + ((size_t)(kk * 4 + (t - 8)) * 512 + lane * 8 + j);
    Wh[dst] = val;
}

// Fused projection-GEMM + tiny attention + maxpool.
// 256 blocks x 512 threads, 1 block/CU (128 KiB LDS). Each block stages the
// K,Q fragments ONCE (single barrier), then its 8 waves free-run over 4
// row-tiles x 16 k-steps with depth-1 software prefetch of A (HBM) and V
// (L2-resident global). Zero barriers in the main loop -- no wave ever
// converges, so HBM latency is hidden by in-flight loads, not by TLP.
__global__ __launch_bounds__(512) void attn_fused_kernel(
        const float* __restrict__ drug,    // [131072, 512] fp32
        const _Float16* __restrict__ Wh,   // swizzled fp16 weights
        float* __restrict__ out)           // [32768, 64] fp32
{
    extern __shared__ __align__(16) char lds[];   // KQ_BYTES = 131072

    const int tid  = threadIdx.x;
    const int wave = tid >> 6;
    const int lane = tid & 63;
    const int quad = lane >> 4;   // A-frag k-subgroup; also b-index in epilogue
    const int l15  = lane & 15;   // A-frag row m; C/D column

    // ---- stage K,Q fragments once: 131072 B, 8 KiB per iteration ----
    {
        const char* gk = (const char*)Wh;
#pragma unroll
        for (int i = 0; i < 16; ++i) {
            const int off = i * 8192 + wave * 1024;   // wave-uniform LDS base
            GLOAD_LDS16(gk + off + lane * 16, lds + off);
        }
    }

    // V fragment pointer: frag (k, tv) at vf[(k*4 + tv)*64] (in half8 units).
    const half8* vf = (const half8*)(Wh + KQ_HALVES) + lane;

    // First row-tile's A and k=0's V, issued under the staging wait.
    const int rowbase = blockIdx.x * ROWS_PER_BLOCK + wave * 16 + l15;
    const float* arow = drug + (size_t)rowbase * FIN + quad * 8;
    float4 a0 = ((const float4*)arow)[0];
    float4 a1 = ((const float4*)arow)[1];
    half8 v0 = vf[0], v1 = vf[64], v2 = vf[128], v3 = vf[192];

    asm volatile("s_waitcnt vmcnt(0)" ::: "memory");
    __builtin_amdgcn_s_barrier();     // all 128 KiB staged; LDS read-only after

    const int bbase = blockIdx.x * (ROWS_PER_BLOCK / 4) + wave * 4 + quad;

#pragma unroll 1
    for (int rt = 0; rt < ROWTILES; ++rt) {
        floatx4 acc[NTILES];
#pragma unroll
        for (int t = 0; t < NTILES; ++t) acc[t] = (floatx4){0.f, 0.f, 0.f, 0.f};

        // at rt's last k-step, prefetch the next row-tile's k=0 data
        const float* pfrow = (rt < ROWTILES - 1) ? arow + 128 * FIN : arow;

#pragma unroll
        for (int k = 0; k < KSTEPS; ++k) {
            // depth-1 prefetch of A(k+1) and V(k+1) (or next tile's k=0)
            float4 n0, n1;
            half8 w0, w1, w2, w3;
            {
                const float4* ap = (k < KSTEPS - 1)
                    ? (const float4*)(arow + (k + 1) * 32)
                    : (const float4*)pfrow;
                n0 = ap[0];
                n1 = ap[1];
                const half8* vp = (k < KSTEPS - 1) ? vf + (k + 1) * 256 : vf;
                w0 = vp[0]; w1 = vp[64]; w2 = vp[128]; w3 = vp[192];
            }

            half8 af;
            af[0] = (_Float16)a0.x; af[1] = (_Float16)a0.y;
            af[2] = (_Float16)a0.z; af[3] = (_Float16)a0.w;
            af[4] = (_Float16)a1.x; af[5] = (_Float16)a1.y;
            af[6] = (_Float16)a1.z; af[7] = (_Float16)a1.w;

            const _Float16* lh = (const _Float16*)(lds + k * 8192);
#pragma unroll
            for (int t = 0; t < 8; ++t) {
                half8 bf = *((const half8*)(lh + t * 512 + lane * 8));
                acc[t] = __builtin_amdgcn_mfma_f32_16x16x32_f16(af, bf, acc[t], 0, 0, 0);
            }
            acc[8]  = __builtin_amdgcn_mfma_f32_16x16x32_f16(af, v0, acc[8],  0, 0, 0);
            acc[9]  = __builtin_amdgcn_mfma_f32_16x16x32_f16(af, v1, acc[9],  0, 0, 0);
            acc[10] = __builtin_amdgcn_mfma_f32_16x16x32_f16(af, v2, acc[10], 0, 0, 0);
            acc[11] = __builtin_amdgcn_mfma_f32_16x16x32_f16(af, v3, acc[11], 0, 0, 0);

            a0 = n0; a1 = n1;
            v0 = w0; v1 = w1; v2 = w2; v3 = w3;
        }
        arow += 128 * FIN;

        // ---- epilogue: per-quad attention over its b ----
        // acc[t] reg r holds C[row = quad*4 + r][col = t*16 + l15]:
        //   tiles 0-3 = k (d = t*16+l15), 4-7 = q, 8-11 = v.
        float p[4][4];
#pragma unroll
        for (int n = 0; n < 4; ++n)
#pragma unroll
            for (int m = 0; m < 4; ++m) {
                float s = 0.f;
#pragma unroll
                for (int t = 0; t < 4; ++t) s += acc[t][n] * acc[4 + t][m];
                p[n][m] = s;
            }

        // reduce the d-dimension across the 16 lanes of this quad
#pragma unroll
        for (int mask = 1; mask < 16; mask <<= 1) {
#pragma unroll
            for (int n = 0; n < 4; ++n)
#pragma unroll
                for (int m = 0; m < 4; ++m)
                    p[n][m] += __shfl_xor(p[n][m], mask, 64);
        }

        // softmax over m (no 1/sqrt(d) scaling), PV, maxpool over n
        float res[4] = {-INFINITY, -INFINITY, -INFINITY, -INFINITY};
#pragma unroll
        for (int n = 0; n < 4; ++n) {
            float mx = fmaxf(fmaxf(p[n][0], p[n][1]), fmaxf(p[n][2], p[n][3]));
            float e0 = __expf(p[n][0] - mx);
            float e1 = __expf(p[n][1] - mx);
            float e2 = __expf(p[n][2] - mx);
            float e3 = __expf(p[n][3] - mx);
            float inv = 1.f / (e0 + e1 + e2 + e3);
#pragma unroll
            for (int t = 0; t < 4; ++t) {
                float o = (e0 * acc[8 + t][0] + e1 * acc[8 + t][1] +
                           e2 * acc[8 + t][2] + e3 * acc[8 + t][3]) * inv;
                res[t] = fmaxf(res[t], o);
            }
        }

        const int b = bbase + rt * 32;
#pragma unroll
        for (int t = 0; t < 4; ++t)
            out[b * 64 + t * 16 + l15] = res[t];
    }
}

extern "C" void kernel_launch(void* const* d_in, const int* in_sizes, int n_in,
                              void* d_out, int out_size, void* d_ws, size_t ws_size,
                              hipStream_t stream) {
    const float* drug = (const float*)d_in[0];
    const float* Wk   = (const float*)d_in[1];
    const float* Wq   = (const float*)d_in[2];
    const float* Wv   = (const float*)d_in[3];
    float* out = (float*)d_out;
    _Float16* Wh = (_Float16*)d_ws;   // 196608 B of scratch

    static bool attr_set = false;
    if (!attr_set) {
        hipFuncSetAttribute((const void*)attn_fused_kernel,
                            hipFuncAttributeMaxDynamicSharedMemorySize, KQ_BYTES);
        attr_set = true;
    }

    convert_w_kernel<<<(WH_ELEMS + 255) / 256, 256, 0, stream>>>(Wk, Wq, Wv, Wh);
    attn_fused_kernel<<<NBLOCKS, 512, KQ_BYTES, stream>>>(drug, Wh, out);
}

// Round 4
// 707.313 us; speedup vs baseline: 1.0013x; 1.0013x over previous
//
#include <hip/hip_runtime.h>
#include <hip/hip_fp16.h>

// Problem constants (fixed by the reference):
//   B=32768, N=4, F_IN=512, D=64  -> GEMM [131072 x 512] x [512 x 192]
#define BTOT   32768
#define FIN    512
#define KSTEPS 16        // 512 / 32
#define NTILES 12        // 192 / 16 (tiles 0-3 = K, 4-7 = Q, 8-11 = V)
#define WH_ELEMS (KSTEPS * NTILES * 64 * 8)   // 98304 halves
#define CHUNK_HALVES (NTILES * 64 * 8)        // old-layout chunk (per k-step)
#define KQ_HALVES (KSTEPS * 8 * 512)          // 65536 halves = 128 KiB (K,Q section)
#define KQ_BYTES  (KQ_HALVES * 2)             // 131072 B staged to LDS
#define WAVES  8
#define ROWTILES 4
#define ROWS_PER_BLOCK (WAVES * 16 * ROWTILES)  // 512
#define NBLOCKS (BTOT * 4 / ROWS_PER_BLOCK)     // 256 = 1 per CU

using half8   = __attribute__((ext_vector_type(8))) _Float16;
using floatx4 = __attribute__((ext_vector_type(4))) float;

// Async global->LDS, 16 B per lane. LDS dest is wave-uniform base + lane*16.
#define GLOAD_LDS16(gp, lp)                                                  \
    __builtin_amdgcn_global_load_lds(                                        \
        (const __attribute__((address_space(1))) void*)(gp),                 \
        (__attribute__((address_space(3))) void*)(lp), 16, 0, 0)

// Convert Wk|Wq|Wv (fp32 [512,64] each) into fp16 MFMA B-fragment order.
// Layout: K,Q section  [k][t=0..7][lane][j]  (128 KiB, staged to LDS once),
//         V  section   [k][t=0..3][lane][j]  ( 64 KiB, stays in global/L2).
// B-operand layout for mfma_f32_16x16x32_f16: lane holds B[k=(lane>>4)*8+j][n=lane&15].
__global__ void convert_w_kernel(const float* __restrict__ Wk,
                                 const float* __restrict__ Wq,
                                 const float* __restrict__ Wv,
                                 _Float16* __restrict__ Wh) {
    int idx = blockIdx.x * blockDim.x + threadIdx.x;
    if (idx >= WH_ELEMS) return;
    int j    = idx & 7;
    int lane = (idx >> 3) & 63;
    int t    = (idx >> 9) % NTILES;
    int kk   = idx / CHUNK_HALVES;
    int k = kk * 32 + (lane >> 4) * 8 + j;
    int n = t * 16 + (lane & 15);
    const float* src = (n < 64) ? Wk : (n < 128) ? Wq : Wv;
    _Float16 val = (_Float16)src[k * 64 + (n & 63)];
    size_t dst = (t < 8)
        ? ((size_t)(kk * 8 + t) * 512 + lane * 8 + j)
        : (size_t)KQ_HALVES + ((size_t)(kk * 4 + (t - 8)) * 512 + lane * 8 + j);
    Wh[dst] = val;
}

// Fused projection-GEMM + tiny attention + maxpool.
// 256 blocks x 512 threads, 1 block/CU (128 KiB LDS). Each block stages the
// K,Q fragments ONCE (single barrier), then its 8 waves free-run over 4
// row-tiles x 16 k-steps with depth-1 software prefetch of A (HBM) and V
// (L2-resident global). Zero barriers in the main loop.
//
// __launch_bounds__(512, 2): 2 waves/SIMD == the 1-block/CU occupancy this
// kernel actually runs at -> VGPR cap 256/wave. Round 3's plain (512) capped
// VGPRs at 128 and spilled ~300 MB of scratch per launch (WRITE_SIZE=309MB),
// which also thrashed L2 and re-fetched V from HBM. This is the fix.
__global__ __launch_bounds__(512, 2) void attn_fused_kernel(
        const float* __restrict__ drug,    // [131072, 512] fp32
        const _Float16* __restrict__ Wh,   // swizzled fp16 weights
        float* __restrict__ out)           // [32768, 64] fp32
{
    extern __shared__ __align__(16) char lds[];   // KQ_BYTES = 131072

    const int tid  = threadIdx.x;
    const int wave = tid >> 6;
    const int lane = tid & 63;
    const int quad = lane >> 4;   // A-frag k-subgroup; also b-index in epilogue
    const int l15  = lane & 15;   // A-frag row m; C/D column

    // ---- stage K,Q fragments once: 131072 B, 8 KiB per iteration ----
    {
        const char* gk = (const char*)Wh;
#pragma unroll
        for (int i = 0; i < 16; ++i) {
            const int off = i * 8192 + wave * 1024;   // wave-uniform LDS base
            GLOAD_LDS16(gk + off + lane * 16, lds + off);
        }
    }

    // V fragment pointer: frag (k, tv) at vf[(k*4 + tv)*64] (in half8 units).
    const half8* vf = (const half8*)(Wh + KQ_HALVES) + lane;

    // First row-tile's A and k=0's V, issued under the staging wait.
    const int rowbase = blockIdx.x * ROWS_PER_BLOCK + wave * 16 + l15;
    const float* arow = drug + (size_t)rowbase * FIN + quad * 8;
    float4 a0 = ((const float4*)arow)[0];
    float4 a1 = ((const float4*)arow)[1];
    half8 v0 = vf[0], v1 = vf[64], v2 = vf[128], v3 = vf[192];

    asm volatile("s_waitcnt vmcnt(0)" ::: "memory");
    __builtin_amdgcn_s_barrier();     // all 128 KiB staged; LDS read-only after

    const int bbase = blockIdx.x * (ROWS_PER_BLOCK / 4) + wave * 4 + quad;

#pragma unroll 1
    for (int rt = 0; rt < ROWTILES; ++rt) {
        floatx4 acc[NTILES];
#pragma unroll
        for (int t = 0; t < NTILES; ++t) acc[t] = (floatx4){0.f, 0.f, 0.f, 0.f};

        // at rt's last k-step, prefetch the next row-tile's k=0 data
        const float* pfrow = (rt < ROWTILES - 1) ? arow + 128 * FIN : arow;

#pragma unroll
        for (int k = 0; k < KSTEPS; ++k) {
            // depth-1 prefetch of A(k+1) and V(k+1) (or next tile's k=0)
            float4 n0, n1;
            half8 w0, w1, w2, w3;
            {
                const float4* ap = (k < KSTEPS - 1)
                    ? (const float4*)(arow + (k + 1) * 32)
                    : (const float4*)pfrow;
                n0 = ap[0];
                n1 = ap[1];
                const half8* vp = (k < KSTEPS - 1) ? vf + (k + 1) * 256 : vf;
                w0 = vp[0]; w1 = vp[64]; w2 = vp[128]; w3 = vp[192];
            }

            half8 af;
            af[0] = (_Float16)a0.x; af[1] = (_Float16)a0.y;
            af[2] = (_Float16)a0.z; af[3] = (_Float16)a0.w;
            af[4] = (_Float16)a1.x; af[5] = (_Float16)a1.y;
            af[6] = (_Float16)a1.z; af[7] = (_Float16)a1.w;

            const _Float16* lh = (const _Float16*)(lds + k * 8192);
#pragma unroll
            for (int t = 0; t < 8; ++t) {
                half8 bf = *((const half8*)(lh + t * 512 + lane * 8));
                acc[t] = __builtin_amdgcn_mfma_f32_16x16x32_f16(af, bf, acc[t], 0, 0, 0);
            }
            acc[8]  = __builtin_amdgcn_mfma_f32_16x16x32_f16(af, v0, acc[8],  0, 0, 0);
            acc[9]  = __builtin_amdgcn_mfma_f32_16x16x32_f16(af, v1, acc[9],  0, 0, 0);
            acc[10] = __builtin_amdgcn_mfma_f32_16x16x32_f16(af, v2, acc[10], 0, 0, 0);
            acc[11] = __builtin_amdgcn_mfma_f32_16x16x32_f16(af, v3, acc[11], 0, 0, 0);

            a0 = n0; a1 = n1;
            v0 = w0; v1 = w1; v2 = w2; v3 = w3;
        }
        arow += 128 * FIN;

        // ---- epilogue: per-quad attention over its b ----
        // acc[t] reg r holds C[row = quad*4 + r][col = t*16 + l15]:
        //   tiles 0-3 = k (d = t*16+l15), 4-7 = q, 8-11 = v.
        float p[4][4];
#pragma unroll
        for (int n = 0; n < 4; ++n)
#pragma unroll
            for (int m = 0; m < 4; ++m) {
                float s = 0.f;
#pragma unroll
                for (int t = 0; t < 4; ++t) s += acc[t][n] * acc[4 + t][m];
                p[n][m] = s;
            }

        // reduce the d-dimension across the 16 lanes of this quad
#pragma unroll
        for (int mask = 1; mask < 16; mask <<= 1) {
#pragma unroll
            for (int n = 0; n < 4; ++n)
#pragma unroll
                for (int m = 0; m < 4; ++m)
                    p[n][m] += __shfl_xor(p[n][m], mask, 64);
        }

        // softmax over m (no 1/sqrt(d) scaling), PV, maxpool over n
        float res[4] = {-INFINITY, -INFINITY, -INFINITY, -INFINITY};
#pragma unroll
        for (int n = 0; n < 4; ++n) {
            float mx = fmaxf(fmaxf(p[n][0], p[n][1]), fmaxf(p[n][2], p[n][3]));
            float e0 = __expf(p[n][0] - mx);
            float e1 = __expf(p[n][1] - mx);
            float e2 = __expf(p[n][2] - mx);
            float e3 = __expf(p[n][3] - mx);
            float inv = 1.f / (e0 + e1 + e2 + e3);
#pragma unroll
            for (int t = 0; t < 4; ++t) {
                float o = (e0 * acc[8 + t][0] + e1 * acc[8 + t][1] +
                           e2 * acc[8 + t][2] + e3 * acc[8 + t][3]) * inv;
                res[t] = fmaxf(res[t], o);
            }
        }

        const int b = bbase + rt * 32;
#pragma unroll
        for (int t = 0; t < 4; ++t)
            out[b * 64 + t * 16 + l15] = res[t];
    }
}

extern "C" void kernel_launch(void* const* d_in, const int* in_sizes, int n_in,
                              void* d_out, int out_size, void* d_ws, size_t ws_size,
                              hipStream_t stream) {
    const float* drug = (const float*)d_in[0];
    const float* Wk   = (const float*)d_in[1];
    const float* Wq   = (const float*)d_in[2];
    const float* Wv   = (const float*)d_in[3];
    float* out = (float*)d_out;
    _Float16* Wh = (_Float16*)d_ws;   // 196608 B of scratch

    static bool attr_set = false;
    if (!attr_set) {
        hipFuncSetAttribute((const void*)attn_fused_kernel,
                            hipFuncAttributeMaxDynamicSharedMemorySize, KQ_BYTES);
        attr_set = true;
    }

    convert_w_kernel<<<(WH_ELEMS + 255) / 256, 256, 0, stream>>>(Wk, Wq, Wv, Wh);
    attn_fused_kernel<<<NBLOCKS, 512, KQ_BYTES, stream>>>(drug, Wh, out);
}

// Round 5
// 371.721 us; speedup vs baseline: 1.9052x; 1.9028x over previous
//
#include <hip/hip_runtime.h>
#include <hip/hip_fp16.h>

// Problem constants (fixed by the reference):
//   B=32768, N=4, F_IN=512, D=64  -> GEMM [131072 x 512] x [512 x 192]
#define BTOT   32768
#define FIN    512
#define KSTEPS 16        // 512 / 32
#define NTILES 12        // 192 / 16 (tiles 0-3 = K, 4-7 = Q, 8-11 = V)
#define WH_ELEMS (KSTEPS * NTILES * 64 * 8)   // 98304 halves
#define CHUNK_HALVES (NTILES * 64 * 8)        // old-layout chunk (per k-step)
#define KQ_HALVES (KSTEPS * 8 * 512)          // 65536 halves = 128 KiB (K,Q section)
#define KQ_BYTES  (KQ_HALVES * 2)             // 131072 B staged to LDS
#define WAVES  8
#define ROWTILES 4
#define ROWS_PER_BLOCK (WAVES * 16 * ROWTILES)  // 512
#define NBLOCKS (BTOT * 4 / ROWS_PER_BLOCK)     // 256 = 1 per CU

using half8   = __attribute__((ext_vector_type(8))) _Float16;
using floatx4 = __attribute__((ext_vector_type(4))) float;

// Async global->LDS, 16 B per lane. LDS dest is wave-uniform base + lane*16.
#define GLOAD_LDS16(gp, lp)                                                  \
    __builtin_amdgcn_global_load_lds(                                        \
        (const __attribute__((address_space(1))) void*)(gp),                 \
        (__attribute__((address_space(3))) void*)(lp), 16, 0, 0)

// Convert Wk|Wq|Wv (fp32 [512,64] each) into fp16 MFMA B-fragment order.
// Layout: K,Q section  [k][t=0..7][lane][j]  (128 KiB, staged to LDS once),
//         V  section   [k][t=0..3][lane][j]  ( 64 KiB, stays in global/L2).
// B-operand layout for mfma_f32_16x16x32_f16: lane holds B[k=(lane>>4)*8+j][n=lane&15].
__global__ void convert_w_kernel(const float* __restrict__ Wk,
                                 const float* __restrict__ Wq,
                                 const float* __restrict__ Wv,
                                 _Float16* __restrict__ Wh) {
    int idx = blockIdx.x * blockDim.x + threadIdx.x;
    if (idx >= WH_ELEMS) return;
    int j    = idx & 7;
    int lane = (idx >> 3) & 63;
    int t    = (idx >> 9) % NTILES;
    int kk   = idx / CHUNK_HALVES;
    int k = kk * 32 + (lane >> 4) * 8 + j;
    int n = t * 16 + (lane & 15);
    const float* src = (n < 64) ? Wk : (n < 128) ? Wq : Wv;
    _Float16 val = (_Float16)src[k * 64 + (n & 63)];
    size_t dst = (t < 8)
        ? ((size_t)(kk * 8 + t) * 512 + lane * 8 + j)
        : (size_t)KQ_HALVES + ((size_t)(kk * 4 + (t - 8)) * 512 + lane * 8 + j);
    Wh[dst] = val;
}

// Fused projection-GEMM + tiny attention + maxpool.
// 256 blocks x 512 threads, 1 block/CU (128 KiB LDS). Each block stages the
// K,Q fragments ONCE (single barrier), then its 8 waves free-run over 4
// row-tiles x 16 k-steps with depth-1 software prefetch of A (HBM) and V
// (L2-resident global). Zero barriers in the main loop.
//
// k-loop is `#pragma unroll 1`: rounds 3/4 fully unrolled it, letting the
// scheduler hoist up to 16 iterations of A/V prefetch loads (~384 regs of
// live loads) -> ~2.3 KB/thread scratch spill (WRITE_SIZE 309 MB). The
// manual depth-1 prefetch already pipelines the loop; bounding the body
// keeps live state ~120 regs and kills the spill.
__global__ __launch_bounds__(512, 2) void attn_fused_kernel(
        const float* __restrict__ drug,    // [131072, 512] fp32
        const _Float16* __restrict__ Wh,   // swizzled fp16 weights
        float* __restrict__ out)           // [32768, 64] fp32
{
    extern __shared__ __align__(16) char lds[];   // KQ_BYTES = 131072

    const int tid  = threadIdx.x;
    const int wave = tid >> 6;
    const int lane = tid & 63;
    const int quad = lane >> 4;   // A-frag k-subgroup; also b-index in epilogue
    const int l15  = lane & 15;   // A-frag row m; C/D column

    // ---- stage K,Q fragments once: 131072 B, 8 KiB per iteration ----
    {
        const char* gk = (const char*)Wh;
#pragma unroll
        for (int i = 0; i < 16; ++i) {
            const int off = i * 8192 + wave * 1024;   // wave-uniform LDS base
            GLOAD_LDS16(gk + off + lane * 16, lds + off);
        }
    }

    // V fragment pointer: frag (k, tv) at vf[(k*4 + tv)*64] (in half8 units).
    const half8* vf = (const half8*)(Wh + KQ_HALVES) + lane;

    // First row-tile's A and k=0's V, issued under the staging wait.
    const int rowbase = blockIdx.x * ROWS_PER_BLOCK + wave * 16 + l15;
    const float* arow = drug + (size_t)rowbase * FIN + quad * 8;
    float4 a0 = ((const float4*)arow)[0];
    float4 a1 = ((const float4*)arow)[1];
    half8 v0 = vf[0], v1 = vf[64], v2 = vf[128], v3 = vf[192];

    asm volatile("s_waitcnt vmcnt(0)" ::: "memory");
    __builtin_amdgcn_s_barrier();     // all 128 KiB staged; LDS read-only after

    const int bbase = blockIdx.x * (ROWS_PER_BLOCK / 4) + wave * 4 + quad;

#pragma unroll 1
    for (int rt = 0; rt < ROWTILES; ++rt) {
        floatx4 acc[NTILES];
#pragma unroll
        for (int t = 0; t < NTILES; ++t) acc[t] = (floatx4){0.f, 0.f, 0.f, 0.f};

        // at rt's last k-step, prefetch the next row-tile's k=0 data
        const float* pfrow = (rt < ROWTILES - 1) ? arow + 128 * FIN : arow;

#pragma unroll 1
        for (int k = 0; k < KSTEPS; ++k) {
            // depth-1 prefetch of A(k+1) and V(k+1) (or next tile's k=0)
            float4 n0, n1;
            half8 w0, w1, w2, w3;
            {
                const float4* ap = (k < KSTEPS - 1)
                    ? (const float4*)(arow + (k + 1) * 32)
                    : (const float4*)pfrow;
                n0 = ap[0];
                n1 = ap[1];
                const half8* vp = (k < KSTEPS - 1) ? vf + (k + 1) * 256 : vf;
                w0 = vp[0]; w1 = vp[64]; w2 = vp[128]; w3 = vp[192];
            }

            half8 af;
            af[0] = (_Float16)a0.x; af[1] = (_Float16)a0.y;
            af[2] = (_Float16)a0.z; af[3] = (_Float16)a0.w;
            af[4] = (_Float16)a1.x; af[5] = (_Float16)a1.y;
            af[6] = (_Float16)a1.z; af[7] = (_Float16)a1.w;

            const _Float16* lh = (const _Float16*)(lds + k * 8192);
#pragma unroll
            for (int t = 0; t < 8; ++t) {
                half8 bf = *((const half8*)(lh + t * 512 + lane * 8));
                acc[t] = __builtin_amdgcn_mfma_f32_16x16x32_f16(af, bf, acc[t], 0, 0, 0);
            }
            acc[8]  = __builtin_amdgcn_mfma_f32_16x16x32_f16(af, v0, acc[8],  0, 0, 0);
            acc[9]  = __builtin_amdgcn_mfma_f32_16x16x32_f16(af, v1, acc[9],  0, 0, 0);
            acc[10] = __builtin_amdgcn_mfma_f32_16x16x32_f16(af, v2, acc[10], 0, 0, 0);
            acc[11] = __builtin_amdgcn_mfma_f32_16x16x32_f16(af, v3, acc[11], 0, 0, 0);

            a0 = n0; a1 = n1;
            v0 = w0; v1 = w1; v2 = w2; v3 = w3;
        }
        arow += 128 * FIN;

        // ---- epilogue: per-quad attention over its b ----
        // acc[t] reg r holds C[row = quad*4 + r][col = t*16 + l15]:
        //   tiles 0-3 = k (d = t*16+l15), 4-7 = q, 8-11 = v.
        float p[4][4];
#pragma unroll
        for (int n = 0; n < 4; ++n)
#pragma unroll
            for (int m = 0; m < 4; ++m) {
                float s = 0.f;
#pragma unroll
                for (int t = 0; t < 4; ++t) s += acc[t][n] * acc[4 + t][m];
                p[n][m] = s;
            }

        // reduce the d-dimension across the 16 lanes of this quad
#pragma unroll
        for (int mask = 1; mask < 16; mask <<= 1) {
#pragma unroll
            for (int n = 0; n < 4; ++n)
#pragma unroll
                for (int m = 0; m < 4; ++m)
                    p[n][m] += __shfl_xor(p[n][m], mask, 64);
        }

        // softmax over m (no 1/sqrt(d) scaling), PV, maxpool over n
        float res[4] = {-INFINITY, -INFINITY, -INFINITY, -INFINITY};
#pragma unroll
        for (int n = 0; n < 4; ++n) {
            float mx = fmaxf(fmaxf(p[n][0], p[n][1]), fmaxf(p[n][2], p[n][3]));
            float e0 = __expf(p[n][0] - mx);
            float e1 = __expf(p[n][1] - mx);
            float e2 = __expf(p[n][2] - mx);
            float e3 = __expf(p[n][3] - mx);
            float inv = 1.f / (e0 + e1 + e2 + e3);
#pragma unroll
            for (int t = 0; t < 4; ++t) {
                float o = (e0 * acc[8 + t][0] + e1 * acc[8 + t][1] +
                           e2 * acc[8 + t][2] + e3 * acc[8 + t][3]) * inv;
                res[t] = fmaxf(res[t], o);
            }
        }

        const int b = bbase + rt * 32;
#pragma unroll
        for (int t = 0; t < 4; ++t)
            out[b * 64 + t * 16 + l15] = res[t];
    }
}

extern "C" void kernel_launch(void* const* d_in, const int* in_sizes, int n_in,
                              void* d_out, int out_size, void* d_ws, size_t ws_size,
                              hipStream_t stream) {
    const float* drug = (const float*)d_in[0];
    const float* Wk   = (const float*)d_in[1];
    const float* Wq   = (const float*)d_in[2];
    const float* Wv   = (const float*)d_in[3];
    float* out = (float*)d_out;
    _Float16* Wh = (_Float16*)d_ws;   // 196608 B of scratch

    static bool attr_set = false;
    if (!attr_set) {
        hipFuncSetAttribute((const void*)attn_fused_kernel,
                            hipFuncAttributeMaxDynamicSharedMemorySize, KQ_BYTES);
        attr_set = true;
    }

    convert_w_kernel<<<(WH_ELEMS + 255) / 256, 256, 0, stream>>>(Wk, Wq, Wv, Wh);
    attn_fused_kernel<<<NBLOCKS, 512, KQ_BYTES, stream>>>(drug, Wh, out);
}

// Round 6
// 368.638 us; speedup vs baseline: 1.9211x; 1.0084x over previous
//
#include <hip/hip_runtime.h>
#include <hip/hip_fp16.h>

// Problem constants (fixed by the reference):
//   B=32768, N=4, F_IN=512, D=64  -> GEMM [131072 x 512] x [512 x 192]
#define BTOT   32768
#define FIN    512
#define KSTEPS 16        // 512 / 32
#define NTILES 12        // 192 / 16 (tiles 0-3 = K, 4-7 = Q, 8-11 = V)
#define WH_ELEMS (KSTEPS * NTILES * 64 * 8)   // 98304 halves
// Weight buffer sections (halves):
//   [0,      65536): K,Q tiles (t=0..7)  [k][t][lane][j]  -> LDS (128 KiB)
//   [65536,  81920): V tiles 0,1         [k][tv][lane][j] -> LDS (32 KiB)
//   [81920,  98304): V tiles 2,3         [k][tv][lane][j] -> stays global/L2
#define KQ_HALVES  65536
#define V23_BASE   81920
#define LDS_BYTES  163840    // 160 KiB = full LDS pool (AITER precedent)
#define WAVES  8
#define ROWS_PER_BLOCK 512
#define NBLOCKS (BTOT * 4 / ROWS_PER_BLOCK)   // 256 = 1 per CU

using half8   = __attribute__((ext_vector_type(8))) _Float16;
using floatx4 = __attribute__((ext_vector_type(4))) float;

// Async global->LDS, 16 B per lane. LDS dest is wave-uniform base + lane*16.
#define GLOAD_LDS16(gp, lp)                                                  \
    __builtin_amdgcn_global_load_lds(                                        \
        (const __attribute__((address_space(1))) void*)(gp),                 \
        (__attribute__((address_space(3))) void*)(lp), 16, 0, 0)

// Convert Wk|Wq|Wv (fp32 [512,64] each) into fp16 MFMA B-fragment order,
// in the 3-section layout above.
// B-operand layout for mfma_f32_16x16x32_f16: lane holds B[k=(lane>>4)*8+j][n=lane&15].
__global__ void convert_w_kernel(const float* __restrict__ Wk,
                                 const float* __restrict__ Wq,
                                 const float* __restrict__ Wv,
                                 _Float16* __restrict__ Wh) {
    int idx = blockIdx.x * blockDim.x + threadIdx.x;
    if (idx >= WH_ELEMS) return;
    int j    = idx & 7;
    int lane = (idx >> 3) & 63;
    int t    = (idx >> 9) % NTILES;
    int kk   = idx / (NTILES * 64 * 8);
    int k = kk * 32 + (lane >> 4) * 8 + j;
    int n = t * 16 + (lane & 15);
    const float* src = (n < 64) ? Wk : (n < 128) ? Wq : Wv;
    _Float16 val = (_Float16)src[k * 64 + (n & 63)];
    size_t dst;
    if (t < 8)
        dst = (size_t)(kk * 8 + t) * 512 + lane * 8 + j;
    else if (t < 10)
        dst = (size_t)KQ_HALVES + (size_t)(kk * 2 + (t - 8)) * 512 + lane * 8 + j;
    else
        dst = (size_t)V23_BASE + (size_t)(kk * 2 + (t - 10)) * 512 + lane * 8 + j;
    Wh[dst] = val;
}

// Attention epilogue for one 16-row wave-tile's accumulators.
// acc[t] reg r = C[row=quad*4+r][col=t*16+l15]; tiles 0-3=K, 4-7=Q, 8-11=V.
__device__ __forceinline__ void attn_epilogue(const floatx4 (&acc)[NTILES],
                                              float* __restrict__ out,
                                              int b, int l15) {
    float p[4][4];
#pragma unroll
    for (int n = 0; n < 4; ++n)
#pragma unroll
        for (int m = 0; m < 4; ++m) {
            float s = 0.f;
#pragma unroll
            for (int t = 0; t < 4; ++t) s += acc[t][n] * acc[4 + t][m];
            p[n][m] = s;
        }
    // reduce the d-dimension across the 16 lanes of this quad
#pragma unroll
    for (int mask = 1; mask < 16; mask <<= 1) {
#pragma unroll
        for (int n = 0; n < 4; ++n)
#pragma unroll
            for (int m = 0; m < 4; ++m)
                p[n][m] += __shfl_xor(p[n][m], mask, 64);
    }
    // softmax over m (no 1/sqrt(d) scaling, matching reference), PV, maxpool over n
    float res[4] = {-INFINITY, -INFINITY, -INFINITY, -INFINITY};
#pragma unroll
    for (int n = 0; n < 4; ++n) {
        float mx = fmaxf(fmaxf(p[n][0], p[n][1]), fmaxf(p[n][2], p[n][3]));
        float e0 = __expf(p[n][0] - mx);
        float e1 = __expf(p[n][1] - mx);
        float e2 = __expf(p[n][2] - mx);
        float e3 = __expf(p[n][3] - mx);
        float inv = 1.f / (e0 + e1 + e2 + e3);
#pragma unroll
        for (int t = 0; t < 4; ++t) {
            float o = (e0 * acc[8 + t][0] + e1 * acc[8 + t][1] +
                       e2 * acc[8 + t][2] + e3 * acc[8 + t][3]) * inv;
            res[t] = fmaxf(res[t], o);
        }
    }
#pragma unroll
    for (int t = 0; t < 4; ++t)
        out[b * 64 + t * 16 + l15] = res[t];
}

// Fused projection-GEMM + tiny attention + maxpool.
// 256 blocks x 512 threads, 1 block/CU (160 KiB LDS). Stage 10/12 weight
// tiles (K,Q,V01) into LDS ONCE (single barrier), V23 stays global/L2.
// Each wave then free-runs 2 passes x (2 row-tiles paired) x 16 k-steps:
// every B-fragment read (LDS ds_read or global V23) feeds TWO row-groups'
// MFMAs, halving per-work LDS+VMEM instruction counts. Zero main-loop
// barriers; rounds 0/1/5 showed the binding constraint is per-CU VMEM
// bytes (~11-19 B/cyc effective), so this cuts VMEM 3.1 -> 1.7 MB/CU.
__global__ __launch_bounds__(512, 2) void attn_fused_kernel(
        const float* __restrict__ drug,    // [131072, 512] fp32
        const _Float16* __restrict__ Wh,   // swizzled fp16 weights
        float* __restrict__ out)           // [32768, 64] fp32
{
    extern __shared__ __align__(16) char lds[];   // LDS_BYTES

    const int tid  = threadIdx.x;
    const int wave = tid >> 6;
    const int lane = tid & 63;
    const int quad = lane >> 4;   // A-frag k-subgroup; also b-index in epilogue
    const int l15  = lane & 15;   // A-frag row m; C/D column

    // ---- stage K,Q,V01 once: 163840 B, 8 KiB per iteration ----
    {
        const char* gW = (const char*)Wh;
#pragma unroll
        for (int i = 0; i < 20; ++i) {
            const int off = i * 8192 + wave * 1024;   // wave-uniform LDS base
            GLOAD_LDS16(gW + off + lane * 16, lds + off);
        }
    }

    // V23 fragment pointer: frag (k, tv) at vg[(k*2 + tv)*64] (half8 units).
    const half8* vg = (const half8*)(Wh + V23_BASE) + lane;

    // This lane's A rows: pass p, sub s -> row = base + p*256 + s*128.
    const size_t row0 = (size_t)blockIdx.x * ROWS_PER_BLOCK + wave * 16 + l15;
    const float* abase = drug + row0 * FIN + quad * 8;

    // Prefetch pass 0 / k=0 under the staging wait.
    float4 a00 = ((const float4*)abase)[0];
    float4 a01 = ((const float4*)abase)[1];
    const float* abase1 = abase + 128 * FIN;
    float4 a10 = ((const float4*)abase1)[0];
    float4 a11 = ((const float4*)abase1)[1];
    half8 w0 = vg[0], w1 = vg[64];

    asm volatile("s_waitcnt vmcnt(0)" ::: "memory");
    __builtin_amdgcn_s_barrier();     // all 160 KiB staged; LDS read-only after

#pragma unroll 1
    for (int pass = 0; pass < 2; ++pass) {
        const float* ar0 = abase + (size_t)pass * 256 * FIN;

        floatx4 acc0[NTILES], acc1[NTILES];
#pragma unroll
        for (int t = 0; t < NTILES; ++t) {
            acc0[t] = (floatx4){0.f, 0.f, 0.f, 0.f};
            acc1[t] = (floatx4){0.f, 0.f, 0.f, 0.f};
        }

#pragma unroll 1
        for (int k = 0; k < KSTEPS; ++k) {
            // depth-1 prefetch of A(k+1) both rows and V23(k+1)
            // (at k=15: next pass's k=0, or self for the last pass)
            const int kn = (k < KSTEPS - 1) ? (k + 1) : 0;
            const float* pr0 = (k < KSTEPS - 1)
                ? (ar0 + (k + 1) * 32)
                : (ar0 + ((pass == 0) ? 256 * FIN : 0));
            const float* pr1 = pr0 + 128 * FIN;
            float4 n00 = ((const float4*)pr0)[0];
            float4 n01 = ((const float4*)pr0)[1];
            float4 n10 = ((const float4*)pr1)[0];
            float4 n11 = ((const float4*)pr1)[1];
            const half8* vp = vg + kn * 128;
            half8 nw0 = vp[0], nw1 = vp[64];

            half8 af0, af1;
            af0[0] = (_Float16)a00.x; af0[1] = (_Float16)a00.y;
            af0[2] = (_Float16)a00.z; af0[3] = (_Float16)a00.w;
            af0[4] = (_Float16)a01.x; af0[5] = (_Float16)a01.y;
            af0[6] = (_Float16)a01.z; af0[7] = (_Float16)a01.w;
            af1[0] = (_Float16)a10.x; af1[1] = (_Float16)a10.y;
            af1[2] = (_Float16)a10.z; af1[3] = (_Float16)a10.w;
            af1[4] = (_Float16)a11.x; af1[5] = (_Float16)a11.y;
            af1[6] = (_Float16)a11.z; af1[7] = (_Float16)a11.w;

            // K,Q tiles from LDS: each bf feeds both row-groups.
            const _Float16* lk = (const _Float16*)(lds + k * 8192);
#pragma unroll
            for (int t = 0; t < 8; ++t) {
                half8 bf = *((const half8*)(lk + t * 512 + lane * 8));
                acc0[t] = __builtin_amdgcn_mfma_f32_16x16x32_f16(af0, bf, acc0[t], 0, 0, 0);
                acc1[t] = __builtin_amdgcn_mfma_f32_16x16x32_f16(af1, bf, acc1[t], 0, 0, 0);
            }
            // V tiles 0,1 from LDS
            const _Float16* lv = (const _Float16*)(lds + 131072 + k * 2048);
#pragma unroll
            for (int tv = 0; tv < 2; ++tv) {
                half8 bv = *((const half8*)(lv + tv * 512 + lane * 8));
                acc0[8 + tv] = __builtin_amdgcn_mfma_f32_16x16x32_f16(af0, bv, acc0[8 + tv], 0, 0, 0);
                acc1[8 + tv] = __builtin_amdgcn_mfma_f32_16x16x32_f16(af1, bv, acc1[8 + tv], 0, 0, 0);
            }
            // V tiles 2,3 from prefetched global regs
            acc0[10] = __builtin_amdgcn_mfma_f32_16x16x32_f16(af0, w0, acc0[10], 0, 0, 0);
            acc1[10] = __builtin_amdgcn_mfma_f32_16x16x32_f16(af1, w0, acc1[10], 0, 0, 0);
            acc0[11] = __builtin_amdgcn_mfma_f32_16x16x32_f16(af0, w1, acc0[11], 0, 0, 0);
            acc1[11] = __builtin_amdgcn_mfma_f32_16x16x32_f16(af1, w1, acc1[11], 0, 0, 0);

            a00 = n00; a01 = n01; a10 = n10; a11 = n11;
            w0 = nw0; w1 = nw1;
        }

        const int b0 = blockIdx.x * 128 + pass * 64 + wave * 4 + quad;
        attn_epilogue(acc0, out, b0, l15);
        attn_epilogue(acc1, out, b0 + 32, l15);
    }
}

extern "C" void kernel_launch(void* const* d_in, const int* in_sizes, int n_in,
                              void* d_out, int out_size, void* d_ws, size_t ws_size,
                              hipStream_t stream) {
    const float* drug = (const float*)d_in[0];
    const float* Wk   = (const float*)d_in[1];
    const float* Wq   = (const float*)d_in[2];
    const float* Wv   = (const float*)d_in[3];
    float* out = (float*)d_out;
    _Float16* Wh = (_Float16*)d_ws;   // 196608 B of scratch

    static bool attr_set = false;
    if (!attr_set) {
        hipFuncSetAttribute((const void*)attn_fused_kernel,
                            hipFuncAttributeMaxDynamicSharedMemorySize, LDS_BYTES);
        attr_set = true;
    }

    convert_w_kernel<<<(WH_ELEMS + 255) / 256, 256, 0, stream>>>(Wk, Wq, Wv, Wh);
    attn_fused_kernel<<<NBLOCKS, 512, LDS_BYTES, stream>>>(drug, Wh, out);
}